// Round 4
// baseline (656.587 us; speedup 1.0000x reference)
//
#include <hip/hip_runtime.h>
#include <cstdint>

// GridEncoder forward (torch-ngp semantics), MI355X.
// B = 1048576 points, D=3, L=16 levels, C=2, H=16, per_level_scale=2.0,
// log2_hashmap_size=19, align_corners=False.
//
// Level metadata (from the reference's _level_meta()):
//   res(l)   = 16 << l
//   scale(l) = res - 1            (exact in fp32)
//   dense levels: 0,1,2 (offsets 0, 4920, 40864), base = res+1,
//     idx = cx + cy*base + cz*base^2   (mod size is identity)
//   hashed levels: 3..15, size = 2^19 -> idx = hash & 0x7FFFF
//     offset(l) = l*524288 - 1257368
//   fast_hash primes: (1, 2654435761, 805459861)
//
// R4 changes (on top of R3's level-phased dispatch, which cut FETCH
// 3.58 GB -> 0.47 GB):
//  1. CORNER PAIRING: prime for dim0 is 1, so for the x-pair (ix, ix+1)
//     with ix even, idx1 = idx0 ^ 1 -> both corners live in one aligned
//     16 B float4 -> one global_load_dwordx4 instead of two 8 B gathers.
//     Dense pairs merge when idx is even (idx1 = idx0 + 1). Expected
//     ~25% cut in per-lane gather requests / L2 line traffic (R3 showed
//     the gather is request-throughput bound: 17% HBM, 11% VALU, 86% occ).
//  2. Pass 2 de-nt'd (plain loads/stores) + 4 tiles/block: R3's nt path
//     forced a full HBM round trip (~178 us for 262 MB).

namespace {

using f32x2 = __attribute__((ext_vector_type(2))) float;
using f32x4 = __attribute__((ext_vector_type(4))) float;

__device__ __forceinline__ void level_setup(
    float x, float y, float z, uint32_t l,
    uint32_t idx[8], float w[8], uint32_t* ix_out, bool* hashed_out) {
  uint32_t res = 16u << l;
  float scale = (float)res - 1.0f;

  float px = x * scale + 0.5f;
  float py = y * scale + 0.5f;
  float pz = z * scale + 0.5f;
  float gx = floorf(px), gy = floorf(py), gz = floorf(pz);
  float rx = px - gx, ry = py - gy, rz = pz - gz;
  uint32_t ix = (uint32_t)gx, iy = (uint32_t)gy, iz = (uint32_t)gz;

  uint32_t off = (l >= 3u) ? (l * 524288u - 1257368u)
                           : ((l == 0u) ? 0u : ((l == 1u) ? 4920u : 40864u));
  bool hashed = (l >= 3u);

  uint32_t base = res + 1u;
  uint32_t bb = base * base;
  const uint32_t P2 = 2654435761u, P3 = 805459861u;

  uint32_t dy0 = iy * base, dy1 = dy0 + base;
  uint32_t dz0 = iz * bb,   dz1 = dz0 + bb;
  uint32_t hy0 = iy * P2,   hy1 = hy0 + P2;
  uint32_t hz0 = iz * P3,   hz1 = hz0 + P3;

#pragma unroll
  for (int c = 0; c < 8; ++c) {
    uint32_t cx = ix + (uint32_t)(c & 1);
    uint32_t h = (cx ^ ((c & 2) ? hy1 : hy0) ^ ((c & 4) ? hz1 : hz0)) & 0x7FFFFu;
    uint32_t d = cx + ((c & 2) ? dy1 : dy0) + ((c & 4) ? dz1 : dz0);
    idx[c] = (hashed ? h : d) + off;
  }

  float wx1 = rx, wx0 = 1.0f - rx;
  float wy1 = ry, wy0 = 1.0f - ry;
  float wz1 = rz, wz0 = 1.0f - rz;
#pragma unroll
  for (int c = 0; c < 8; ++c) {
    w[c] = ((c & 1) ? wx1 : wx0) *
           ((c & 2) ? wy1 : wy0) *
           ((c & 4) ? wz1 : wz0);
  }
  *ix_out = ix;
  *hashed_out = hashed;
}

// Gather the 8 corner embeddings with x-pair merging.
// Pair (c, c+1) differs only in bx. Mergeable into one aligned float4 iff:
//   hashed: ix even  (then idx[c+1] == idx[c] ^ 1, same aligned pair)
//   dense:  idx[c] even (then idx[c+1] == idx[c] + 1, same aligned pair)
// off is even for all levels, so parity/alignment survives the +off.
__device__ __forceinline__ void gather8(
    const f32x2* __restrict__ emb, const uint32_t idx[8],
    uint32_t ix, bool hashed, f32x2 e[8]) {
  bool ix_even = (ix & 1u) == 0u;
#pragma unroll
  for (int c = 0; c < 8; c += 2) {
    bool ok = hashed ? ix_even : ((idx[c] & 1u) == 0u);
    if (ok) {
      f32x4 v = *reinterpret_cast<const f32x4*>(&emb[idx[c] & ~1u]);
      bool sw = (idx[c] & 1u) != 0u;   // entry order inside the pair
      e[c].x     = sw ? v.z : v.x;
      e[c].y     = sw ? v.w : v.y;
      e[c + 1].x = sw ? v.x : v.z;
      e[c + 1].y = sw ? v.y : v.w;
    } else {
      e[c]     = emb[idx[c]];
      e[c + 1] = emb[idx[c + 1]];
    }
  }
}

// ---- Pass 1: level-phased gather, writes level-major ws[l*B + p] ----
__global__ __launch_bounds__(256) void gather_lm_kernel(
    const float* __restrict__ in,      // [B,3] in [-1,1]
    const f32x2* __restrict__ emb,     // [7131240] float2
    f32x2* __restrict__ ws,            // [16*B] float2, level-major
    uint32_t B) {
  uint32_t l = blockIdx.y;                       // level: slowest dispatch dim
  uint32_t p = blockIdx.x * 256u + threadIdx.x;  // point
  if (p >= B) return;

  // nt: streaming input must not evict table lines from L2
  float x = (__builtin_nontemporal_load(&in[p * 3 + 0]) + 1.0f) * 0.5f;
  float y = (__builtin_nontemporal_load(&in[p * 3 + 1]) + 1.0f) * 0.5f;
  float z = (__builtin_nontemporal_load(&in[p * 3 + 2]) + 1.0f) * 0.5f;

  uint32_t idx[8];
  float w[8];
  uint32_t ix;
  bool hashed;
  level_setup(x, y, z, l, idx, w, &ix, &hashed);

  f32x2 e[8];
  gather8(emb, idx, ix, hashed, e);

  float o0 = 0.0f, o1 = 0.0f;
#pragma unroll
  for (int c = 0; c < 8; ++c) {
    o0 = fmaf(w[c], e[c].x, o0);
    o1 = fmaf(w[c], e[c].y, o1);
  }

  f32x2 r; r.x = o0; r.y = o1;
  // nt store: ws is a one-shot stream; don't let it evict table lines
  __builtin_nontemporal_store(r, &ws[(size_t)l * B + p]);
}

// ---- Pass 2: transpose level-major ws -> point-major out ----
// 4 tiles of 256 points per block; plain loads/stores (let L2/L3 help).
__global__ __launch_bounds__(256) void transpose_kernel(
    const f32x2* __restrict__ ws,   // [16*B] level-major
    f32x4* __restrict__ out,        // [B*8] float4 == [B,16,2] floats
    uint32_t B) {
  __shared__ f32x2 lds[16 * 257];
  uint32_t tid = threadIdx.x;

  for (uint32_t t = 0; t < 4u; ++t) {
    uint32_t p0 = (blockIdx.x * 4u + t) * 256u;
    if (p0 >= B) break;

#pragma unroll
    for (uint32_t l = 0; l < 16u; ++l) {
      lds[l * 257u + tid] = ws[(size_t)l * B + p0 + tid];
    }
    __syncthreads();

#pragma unroll
    for (uint32_t m = 0; m < 8u; ++m) {
      uint32_t lin = m * 256u + tid;   // point-in-tile*8 + float4-slot
      uint32_t q = lin >> 3;
      uint32_t j2 = lin & 7u;
      f32x2 a = lds[(2u * j2)      * 257u + q];
      f32x2 b = lds[(2u * j2 + 1u) * 257u + q];
      f32x4 v; v.x = a.x; v.y = a.y; v.z = b.x; v.w = b.y;
      out[(size_t)p0 * 8u + lin] = v;   // lane-contiguous 16 B
    }
    __syncthreads();
  }
}

// ---- Fallback (ws too small): single-pass kernel ----
__global__ __launch_bounds__(256) void grid_encode_fallback(
    const float* __restrict__ in, const f32x2* __restrict__ emb,
    f32x4* __restrict__ out, uint32_t B) {
  uint32_t p = blockIdx.x * 256u + threadIdx.x;
  if (p >= B) return;
  float x = (in[p * 3 + 0] + 1.0f) * 0.5f;
  float y = (in[p * 3 + 1] + 1.0f) * 0.5f;
  float z = (in[p * 3 + 2] + 1.0f) * 0.5f;
#pragma unroll 1
  for (uint32_t l = 0; l < 16u; l += 2u) {
    uint32_t ia[8], ib[8]; float wa[8], wb[8];
    uint32_t ixa, ixb; bool ha, hb;
    level_setup(x, y, z, l, ia, wa, &ixa, &ha);
    level_setup(x, y, z, l + 1u, ib, wb, &ixb, &hb);
    f32x2 ea[8], eb[8];
    gather8(emb, ia, ixa, ha, ea);
    gather8(emb, ib, ixb, hb, eb);
    float a0 = 0, a1 = 0, b0 = 0, b1 = 0;
#pragma unroll
    for (int c = 0; c < 8; ++c) {
      a0 = fmaf(wa[c], ea[c].x, a0);
      a1 = fmaf(wa[c], ea[c].y, a1);
      b0 = fmaf(wb[c], eb[c].x, b0);
      b1 = fmaf(wb[c], eb[c].y, b1);
    }
    f32x4 v; v.x = a0; v.y = a1; v.z = b0; v.w = b1;
    out[(size_t)p * 8u + (l >> 1)] = v;
  }
}

}  // namespace

extern "C" void kernel_launch(void* const* d_in, const int* in_sizes, int n_in,
                              void* d_out, int out_size, void* d_ws, size_t ws_size,
                              hipStream_t stream) {
  (void)n_in; (void)out_size;
  const float* in = (const float*)d_in[0];
  const f32x2* emb = (const f32x2*)d_in[1];
  f32x4* out = (f32x4*)d_out;
  uint32_t B = (uint32_t)(in_sizes[0] / 3);
  uint32_t pblocks = (B + 255u) / 256u;

  size_t ws_needed = (size_t)16 * B * sizeof(f32x2);   // 128 MiB at B=1M
  if (ws_size >= ws_needed) {
    f32x2* ws = (f32x2*)d_ws;
    hipLaunchKernelGGL(gather_lm_kernel, dim3(pblocks, 16), dim3(256), 0,
                       stream, in, emb, ws, B);
    uint32_t tblocks = (pblocks + 3u) / 4u;
    hipLaunchKernelGGL(transpose_kernel, dim3(tblocks), dim3(256), 0,
                       stream, ws, out, B);
  } else {
    hipLaunchKernelGGL(grid_encode_fallback, dim3(pblocks), dim3(256), 0,
                       stream, in, emb, out, B);
  }
}